// Round 1
// baseline (6058.286 us; speedup 1.0000x reference)
//
#include <hip/hip_runtime.h>
#include <hip/hip_bf16.h>

// ---- problem constants ----
#define BS     8
#define NN     4096
#define KK     32
#define DD     64
#define TT     32
#define HSZ    256      // HS == HM
#define CMEM   32
#define DLM_   2048
#define MODIN  225      // K + 3D + 1
#define MODOUT 97       // K + 1 + D
#define HMOD_  64
#define PAIRS  32       // (b,n) pairs per step-block

__device__ __forceinline__ float fast_tanh(float x) {
    x = fminf(fmaxf(x, -15.f), 15.f);
    float e = __expf(2.f * x);
    return (e - 1.f) / (e + 1.f);
}
__device__ __forceinline__ float fast_sigmoid(float x) {
    x = fminf(fmaxf(x, -30.f), 30.f);
    return 1.f / (1.f + __expf(-x));
}

// ---------------- pack W_in slices contiguous ----------------
__global__ __launch_bounds__(256) void pack_weights(const float* __restrict__ sw1,
                                                    const float* __restrict__ mw1,
                                                    float* __restrict__ SWIN,
                                                    float* __restrict__ MWH) {
    int idx = blockIdx.x * 256 + threadIdx.x;
    if (idx < HSZ * DD) {
        int j = idx >> 6, d = idx & 63;
        SWIN[idx] = sw1[(size_t)j * 193 + d];   // state_w1[:, :64]
        MWH[idx]  = mw1[(size_t)j * 192 + d];   // msg_w1[:, :64]
    }
}

// ---------------- preamble: per-neuron modulation ----------------
__global__ __launch_bounds__(256) void preamble(
    const float* __restrict__ h0, const float* __restrict__ msg0,
    const float* __restrict__ w_conn, const float* __restrict__ decay,
    const float* __restrict__ prim_in, const float* __restrict__ hebb,
    const float* __restrict__ sw1, const float* __restrict__ sb1,
    const float* __restrict__ mw1, const float* __restrict__ mb1,
    const float* __restrict__ mod_w1, const float* __restrict__ mod_b1,
    const float* __restrict__ mod_w2, const float* __restrict__ mod_b2,
    const float* __restrict__ nid,
    float* __restrict__ W_SIG, float* __restrict__ DEC,
    float* __restrict__ STC, float* __restrict__ MSC,
    float* __restrict__ HBUF, float* __restrict__ MBUF) {
    __shared__ float x[BS][MODIN];
    __shared__ float hid[BS][HMOD_];
    __shared__ float prim[BS][DD];
    __shared__ float dec_l[BS];
    __shared__ float scale_l[BS];
    __shared__ float nid_l[DD];
    __shared__ float nidc_s[HSZ];
    __shared__ float nidc_m[HSZ];

    const int n = blockIdx.x;
    const int tid = threadIdx.x;
    if (tid < DD) nid_l[tid] = nid[(size_t)n * DD + tid];

    // build mod_input for all 8 batches
    for (int i = tid; i < BS * MODIN; i += 256) {
        int b = i / MODIN, c = i % MODIN;
        size_t bn = (size_t)b * NN + n;
        float v;
        if (c < KK)            v = hebb[bn * KK + c];
        else if (c < KK + DD)  v = h0[bn * DD + (c - KK)];
        else if (c == 96)      v = decay[bn];
        else if (c < 161)      v = prim_in[bn * DD + (c - 97)];
        else                   v = nid[(size_t)n * DD + (c - 161)];
        x[b][c] = v;
    }
    __syncthreads();

    // hid = tanh(mod_w1 @ x + b1): 512 dots of len 225; thread does 2 batches
    {
        int hh = tid & 63;
        int b0 = tid >> 6;  // 0..3; pairs with b0+4
        const float* w1p = mod_w1 + ((size_t)n * HMOD_ + hh) * MODIN;
        float acc0 = mod_b1[(size_t)n * HMOD_ + hh];
        float acc1 = acc0;
        for (int i = 0; i < MODIN; ++i) {
            float w = w1p[i];
            acc0 += x[b0][i] * w;
            acc1 += x[b0 + 4][i] * w;
        }
        hid[b0][hh]     = fast_tanh(acc0);
        hid[b0 + 4][hh] = fast_tanh(acc1);
    }
    __syncthreads();

    // delta = hid @ mod_w2 + b2, and scatter into w_sig / decay / prim
    for (int idx = tid; idx < BS * MODOUT; idx += 256) {
        int b = idx / MODOUT, o = idx % MODOUT;
        size_t bn = (size_t)b * NN + n;
        const float* w2p = mod_w2 + (size_t)n * HMOD_ * MODOUT + o;
        float acc = mod_b2[(size_t)n * MODOUT + o];
        for (int h = 0; h < HMOD_; ++h) acc += hid[b][h] * w2p[(size_t)h * MODOUT];
        if (o < KK) {
            W_SIG[bn * KK + o] = fast_sigmoid(w_conn[bn * KK + o] + acc);
        } else if (o == KK) {
            float dl = decay[bn] + acc;
            dec_l[b] = dl;
            DEC[bn] = fast_sigmoid(dl);
        } else {
            prim[b][o - 33] = prim_in[bn * DD + (o - 33)] + acc;
        }
    }
    __syncthreads();

    // RMS-normalize prim per batch
    if (tid < BS) {
        float ss = 0.f;
        for (int d2 = 0; d2 < DD; ++d2) { float p = prim[tid][d2]; ss += p * p; }
        scale_l[tid] = rsqrtf(ss / DD + 1e-6f);
    }
    __syncthreads();
    for (int v = tid; v < BS * DD; v += 256) {
        int b = v >> 6, d2 = v & 63;
        prim[b][d2] *= scale_l[b];
    }
    // nid-dependent (batch-independent) parts of the consts + biases
    {
        int j = tid;  // 256 threads == HSZ
        float as = 0.f, am = 0.f;
        const float* sp = sw1 + (size_t)j * 193 + 128;
        const float* mp = mw1 + (size_t)j * 192 + 128;
        for (int d2 = 0; d2 < DD; ++d2) { as += nid_l[d2] * sp[d2]; am += nid_l[d2] * mp[d2]; }
        nidc_s[j] = as + sb1[j];
        nidc_m[j] = am + mb1[j];
    }
    __syncthreads();

    // state_const / msg_const
    for (int v = tid; v < BS * HSZ; v += 256) {
        int b = v >> 8, j = v & 255;
        const float* sp = sw1 + (size_t)j * 193 + 64;
        const float* mp = mw1 + (size_t)j * 192 + 64;
        float as = nidc_s[j] + dec_l[b] * sw1[(size_t)j * 193 + 192];
        float am = nidc_m[j];
        for (int d2 = 0; d2 < DD; ++d2) { float p = prim[b][d2]; as += p * sp[d2]; am += p * mp[d2]; }
        size_t bn = (size_t)b * NN + n;
        STC[bn * HSZ + j] = as;
        MSC[bn * HSZ + j] = am;
    }
    // init state buffers
    for (int v = tid; v < BS * DD; v += 256) {
        int b = v >> 6, d2 = v & 63;
        size_t bn = (size_t)b * NN + n;
        HBUF[bn * DD + d2] = h0[bn * DD + d2];
        MBUF[bn * DD + d2] = msg0[bn * DD + d2];
    }
}

// ---------------- step kernel 1: h update ----------------
__global__ __launch_bounds__(256) void step_h(
    int t,
    const float* __restrict__ cc, const int* __restrict__ conn,
    const float* __restrict__ sw2, const float* __restrict__ sb2,
    const float* __restrict__ W_SIG, const float* __restrict__ DEC,
    const float* __restrict__ STC, const float* __restrict__ SWIN,
    float* __restrict__ HBUF, const float* __restrict__ MBUF) {
    __shared__ float recv_l[PAIRS][DD];
    __shared__ float hid_l[PAIRS][HSZ];
    const int tid = threadIdx.x;
    const size_t base = (size_t)blockIdx.x * PAIRS;
    const int b = (int)(base >> 12);

    // phase 1: recv gather + inject
    for (int v = tid; v < PAIRS * DD; v += 256) {
        int p = v >> 6, d = v & 63;
        size_t bn = base + p;
        int n = (int)(bn & (NN - 1));
        const int* cp = conn + (size_t)n * KK;
        const float* wp = W_SIG + bn * KK;
        float acc = 0.f;
        #pragma unroll 8
        for (int k = 0; k < KK; ++k) {
            int src = cp[k];
            acc += wp[k] * MBUF[((size_t)b * NN + src) * DD + d];
        }
        if ((n & 127) < 4) {  // inject rows
            int s = n >> 7;
            acc += cc[((size_t)b * TT + t) * DLM_ + s * DD + d];
        }
        recv_l[p][d] = acc;
    }
    __syncthreads();

    // phase 2: hid = tanh(recv @ W_in^T + state_const); thread j holds weight row
    {
        int j = tid;
        float w[DD];
        const float4* wp = (const float4*)(SWIN + (size_t)j * DD);
        #pragma unroll
        for (int q = 0; q < 16; ++q) {
            float4 f = wp[q];
            w[4*q] = f.x; w[4*q+1] = f.y; w[4*q+2] = f.z; w[4*q+3] = f.w;
        }
        for (int p = 0; p < PAIRS; ++p) {
            float acc = STC[(base + p) * HSZ + j];
            const float4* rp = (const float4*)recv_l[p];
            #pragma unroll
            for (int q = 0; q < 16; ++q) {
                float4 r = rp[q];
                acc += w[4*q]*r.x + w[4*q+1]*r.y + w[4*q+2]*r.z + w[4*q+3]*r.w;
            }
            hid_l[p][j] = fast_tanh(acc);
        }
    }
    __syncthreads();

    // phase 3: upd = tanh(hid @ W2^T + b2); h = d*h + (1-d)*upd
    {
        int d2 = tid & 63;
        int pg = tid >> 6;
        float acc[8];
        #pragma unroll
        for (int i = 0; i < 8; ++i) acc[i] = sb2[d2];
        const float* w2 = sw2 + (size_t)d2 * HSZ;
        for (int j0 = 0; j0 < HSZ; j0 += 16) {
            float wc[16];
            #pragma unroll
            for (int q = 0; q < 16; ++q) wc[q] = w2[j0 + q];
            #pragma unroll
            for (int i = 0; i < 8; ++i) {
                int p = pg * 8 + i;
                const float4* hp = (const float4*)&hid_l[p][j0];
                float a = acc[i];
                #pragma unroll
                for (int q = 0; q < 4; ++q) {
                    float4 hv = hp[q];
                    a += wc[4*q]*hv.x + wc[4*q+1]*hv.y + wc[4*q+2]*hv.z + wc[4*q+3]*hv.w;
                }
                acc[i] = a;
            }
        }
        #pragma unroll
        for (int i = 0; i < 8; ++i) {
            int p = pg * 8 + i;
            size_t bn = base + p;
            float dv = DEC[bn];
            float hold = HBUF[bn * DD + d2];
            float upd = fast_tanh(acc[i]);
            HBUF[bn * DD + d2] = dv * hold + (1.f - dv) * upd;
        }
    }
}

// ---------------- step kernel 2: msg update + readout ----------------
__global__ __launch_bounds__(256) void step_msg(
    int t,
    const float* __restrict__ mw2, const float* __restrict__ mb2,
    const float* __restrict__ nid,
    const float* __restrict__ MSC, const float* __restrict__ MWH,
    const float* __restrict__ HBUF, float* __restrict__ MBUF,
    float* __restrict__ out) {
    __shared__ float h_l[PAIRS][DD];      // reused for msg in phase 3
    __shared__ float mh_l[PAIRS][HSZ];
    const int tid = threadIdx.x;
    const size_t base = (size_t)blockIdx.x * PAIRS;
    const int b = (int)(base >> 12);

    for (int v = tid; v < PAIRS * DD; v += 256) {
        int p = v >> 6, d = v & 63;
        h_l[p][d] = HBUF[(base + p) * DD + d];
    }
    __syncthreads();

    // mh = tanh(h @ msg_w_h^T + msg_const)
    {
        int j = tid;
        float w[DD];
        const float4* wp = (const float4*)(MWH + (size_t)j * DD);
        #pragma unroll
        for (int q = 0; q < 16; ++q) {
            float4 f = wp[q];
            w[4*q] = f.x; w[4*q+1] = f.y; w[4*q+2] = f.z; w[4*q+3] = f.w;
        }
        for (int p = 0; p < PAIRS; ++p) {
            float acc = MSC[(base + p) * HSZ + j];
            const float4* rp = (const float4*)h_l[p];
            #pragma unroll
            for (int q = 0; q < 16; ++q) {
                float4 r = rp[q];
                acc += w[4*q]*r.x + w[4*q+1]*r.y + w[4*q+2]*r.z + w[4*q+3]*r.w;
            }
            mh_l[p][j] = fast_tanh(acc);
        }
    }
    __syncthreads();

    // msg = tanh(mh @ msg_w2^T + b2) + nid
    {
        int d2 = tid & 63;
        int pg = tid >> 6;
        float acc[8];
        #pragma unroll
        for (int i = 0; i < 8; ++i) acc[i] = mb2[d2];
        const float* w2 = mw2 + (size_t)d2 * HSZ;
        for (int j0 = 0; j0 < HSZ; j0 += 16) {
            float wc[16];
            #pragma unroll
            for (int q = 0; q < 16; ++q) wc[q] = w2[j0 + q];
            #pragma unroll
            for (int i = 0; i < 8; ++i) {
                int p = pg * 8 + i;
                const float4* hp = (const float4*)&mh_l[p][j0];
                float a = acc[i];
                #pragma unroll
                for (int q = 0; q < 4; ++q) {
                    float4 hv = hp[q];
                    a += wc[4*q]*hv.x + wc[4*q+1]*hv.y + wc[4*q+2]*hv.z + wc[4*q+3]*hv.w;
                }
                acc[i] = a;
            }
        }
        #pragma unroll
        for (int i = 0; i < 8; ++i) {
            int p = pg * 8 + i;
            size_t bn = base + p;
            int n = (int)(bn & (NN - 1));
            float m = fast_tanh(acc[i]) + nid[(size_t)n * DD + d2];
            MBUF[bn * DD + d2] = m;
            h_l[p][d2] = m;  // stash for readout (h_l no longer needed)
        }
    }
    __syncthreads();

    // readout: rows n%128 in 124..127 live at p=28..31 of the block with n_base%128==96
    int n_base = (int)(base & (NN - 1));
    if ((n_base & 127) == 96 && tid < DD) {
        int s = n_base >> 7;
        float r = 0.25f * (h_l[28][tid] + h_l[29][tid] + h_l[30][tid] + h_l[31][tid]);
        out[((size_t)b * TT + t) * DLM_ + s * DD + tid] = r;
    }
}

extern "C" void kernel_launch(void* const* d_in, const int* in_sizes, int n_in,
                              void* d_out, int out_size, void* d_ws, size_t ws_size,
                              hipStream_t stream) {
    const float* cc      = (const float*)d_in[0];
    const float* h0      = (const float*)d_in[1];
    const float* msg0    = (const float*)d_in[2];
    const float* w_conn  = (const float*)d_in[3];
    const float* decay   = (const float*)d_in[4];
    const float* prim    = (const float*)d_in[5];
    const float* hebb    = (const float*)d_in[6];
    const float* sw1     = (const float*)d_in[7];
    const float* sb1     = (const float*)d_in[8];
    const float* sw2     = (const float*)d_in[9];
    const float* sb2     = (const float*)d_in[10];
    const float* mw1     = (const float*)d_in[11];
    const float* mb1     = (const float*)d_in[12];
    const float* mw2     = (const float*)d_in[13];
    const float* mb2     = (const float*)d_in[14];
    const float* mod_w1  = (const float*)d_in[15];
    const float* mod_b1  = (const float*)d_in[16];
    const float* mod_w2  = (const float*)d_in[17];
    const float* mod_b2  = (const float*)d_in[18];
    const float* nid     = (const float*)d_in[19];
    const int*   conn    = (const int*)d_in[20];

    float* ws    = (float*)d_ws;
    float* W_SIG = ws;                                  // BS*NN*KK
    float* DEC   = W_SIG + (size_t)BS * NN * KK;        // BS*NN
    float* STC   = DEC   + (size_t)BS * NN;             // BS*NN*HSZ
    float* MSC   = STC   + (size_t)BS * NN * HSZ;       // BS*NN*HSZ
    float* HBUF  = MSC   + (size_t)BS * NN * HSZ;       // BS*NN*DD
    float* MBUF  = HBUF  + (size_t)BS * NN * DD;        // BS*NN*DD
    float* SWIN  = MBUF  + (size_t)BS * NN * DD;        // HSZ*DD
    float* MWH   = SWIN  + (size_t)HSZ * DD;            // HSZ*DD
    float* out   = (float*)d_out;

    hipLaunchKernelGGL(pack_weights, dim3(64), dim3(256), 0, stream, sw1, mw1, SWIN, MWH);
    hipLaunchKernelGGL(preamble, dim3(NN), dim3(256), 0, stream,
                       h0, msg0, w_conn, decay, prim, hebb,
                       sw1, sb1, mw1, mb1, mod_w1, mod_b1, mod_w2, mod_b2, nid,
                       W_SIG, DEC, STC, MSC, HBUF, MBUF);
    const int step_grid = BS * NN / PAIRS;  // 1024
    for (int t = 0; t < TT; ++t) {
        hipLaunchKernelGGL(step_h, dim3(step_grid), dim3(256), 0, stream,
                           t, cc, conn, sw2, sb2, W_SIG, DEC, STC, SWIN, HBUF, MBUF);
        hipLaunchKernelGGL(step_msg, dim3(step_grid), dim3(256), 0, stream,
                           t, mw2, mb2, nid, MSC, MWH, HBUF, MBUF, out);
    }
}